// Round 10
// baseline (299.079 us; speedup 1.0000x reference)
//
#include <hip/hip_runtime.h>

typedef __bf16 bf16x8 __attribute__((ext_vector_type(8)));
typedef float f32x4 __attribute__((ext_vector_type(4)));
typedef unsigned int u32x4 __attribute__((ext_vector_type(4)));
typedef unsigned int u32x2 __attribute__((ext_vector_type(2)));
typedef unsigned short u16x8 __attribute__((ext_vector_type(8)));

#define MFMA_BF16(a, b, c) __builtin_amdgcn_mfma_f32_16x16x32_bf16((a), (b), (c), 0, 0, 0)

// 0.125 (1/sqrt(64)) * log2(e): folded into Q so softmax uses raw exp2
#define QSCALE 0.18033688011112043f

__device__ __forceinline__ unsigned short f2bf(float f) {
    unsigned int u = __builtin_bit_cast(unsigned int, f);
    u += 0x7FFFu + ((u >> 16) & 1u);
    return (unsigned short)(u >> 16);
}

// manual RNE pack (bit-identical to f2bf pairs) — numerically sensitive V path stays RNE.
__device__ __forceinline__ unsigned int pack_bf16_rne(float a, float b) {
    unsigned int ua = __builtin_bit_cast(unsigned int, a);
    unsigned int ub = __builtin_bit_cast(unsigned int, b);
    ua += 0x7FFFu + ((ua >> 16) & 1u);
    ub += 0x7FFFu + ((ub >> 16) & 1u);
    return __builtin_amdgcn_perm(ub, ua, 0x07060302);
}

// cheap pack for P (values in [0,1], self-normalizing) — validated earlier
#if __has_builtin(__builtin_amdgcn_cvt_pk_bf16_f32)
typedef __bf16 bf16x2 __attribute__((ext_vector_type(2)));
__device__ __forceinline__ unsigned int pack_bf16(float a, float b) {
    return __builtin_bit_cast(unsigned int, __builtin_amdgcn_cvt_pk_bf16_f32(a, b));
}
#else
__device__ __forceinline__ unsigned int pack_bf16(float a, float b) {
    return pack_bf16_rne(a, b);
}
#endif

#if __has_builtin(__builtin_amdgcn_exp2f)
__device__ __forceinline__ float fast_exp2(float x) { return __builtin_amdgcn_exp2f(x); }
#else
__device__ __forceinline__ float fast_exp2(float x) { return exp2f(x); }
#endif

__device__ __forceinline__ bf16x8 ldfrag(const unsigned short* p) {
    return __builtin_bit_cast(bf16x8, *(const u32x4*)p);
}

// async global->LDS, 16B per lane; LDS dst = wave-uniform base + lane*16B
typedef const __attribute__((address_space(1))) void* gas_t;
typedef __attribute__((address_space(3))) void* las_t;
__device__ __forceinline__ void dma16(const unsigned short* g, unsigned short* l) {
    __builtin_amdgcn_global_load_lds((gas_t)(const void*)g, (las_t)(void*)l, 16, 0, 0);
}

// drain this wave's outstanding DMA/LDS ops, then block barrier (full-drain form,
// used by the attn kernel — its schedule is the validated R2 champion).
__device__ __forceinline__ void pipeline_barrier() {
    __builtin_amdgcn_s_waitcnt(0);
    __syncthreads();
}

// ---------------- fused conversion kernel (confirmed -5.4 µs) ----------------
// blocks [0,4096): x -> bf16.  [4096,5632): Wq/Wk/Wv transpose+cvt.  [5632,6144): Wo^T cvt.

__global__ void cvt_fused_kernel(const float* __restrict__ x,
                                 const float* __restrict__ Wq, const float* __restrict__ Wk,
                                 const float* __restrict__ Wv, const float* __restrict__ Wo,
                                 unsigned short* __restrict__ xb, unsigned short* __restrict__ WT,
                                 unsigned short* __restrict__ WoT) {
    const int b = blockIdx.x;
    const int tid = threadIdx.x;
    if (b < 4096) {
        long long t = (long long)b * 256 + tid;
        const f32x4* p = (const f32x4*)x + t * 2;
        f32x4 v0 = p[0], v1 = p[1];
        u16x8 o;
        o[0] = f2bf(v0[0]); o[1] = f2bf(v0[1]); o[2] = f2bf(v0[2]); o[3] = f2bf(v0[3]);
        o[4] = f2bf(v1[0]); o[5] = f2bf(v1[1]); o[6] = f2bf(v1[2]); o[7] = f2bf(v1[3]);
        *((u16x8*)xb + t) = o;
    } else if (b < 5632) {
        int bb = b - 4096;
        int bx = bb % 12, by = bb / 12;
        int n = bx * 256 + tid;
        int d0 = by * 8;
        int proj = n >> 10, rem = n & 1023, h = rem >> 6, e = rem & 63;
        const float* W = (proj == 0) ? Wq : (proj == 1) ? Wk : Wv;
        const float* src = W + (size_t)h * 65536 + (size_t)d0 * 64 + e;
        u16x8 o;
#pragma unroll
        for (int j = 0; j < 8; j++) o[j] = f2bf(src[j * 64]);
        *(u16x8*)(WT + (size_t)n * 1024 + d0) = o;
    } else {
        int bb = b - 5632;
        int bx = bb % 4, by = bb / 4;
        int n = bx * 256 + tid;
        int d0 = by * 8;
        const float* src = Wo + (size_t)d0 * 1024 + n;
        u16x8 o;
#pragma unroll
        for (int j = 0; j < 8; j++) o[j] = f2bf(src[j * 1024]);
        *(u16x8*)(WoT + (size_t)n * 1024 + d0) = o;
    }
}

// ---------------- GEMM kernels: BK=64, counted-vmcnt DMA pipeline (R13) ----------------
// 128x128 tile, BK=64 (was 32): barriers per kernel halved, 32 MFMA per barrier-pair.
// Counted waits (T4): raw s_barrier + inline vmcnt(4) — next tile's 4 loads stay in
// flight across the wait; vmcnt(0) only on the final tile. LDS [2][128][64] u16 per
// operand = 64 KiB/block -> still 2 blocks/CU. Staging/fragment geometry identical to
// the attn K-tile (validated): 8-row dma16 groups, source swizzle chunk^(row&7),
// frag chunk (kc*4+quad)^(lr&7) -> <=2-way (free) b128.
// Wait-count audit (per wave, steady state): entry outstanding = A(t)[4] then B(t)[4];
// vmcnt(4) drains A(t); issue A(t+1)[4]; vmcnt(4) drains B(t); read B-frags; issue
// B(t+1)[4]; compute. WAR on buf[cur^1] is separated by the iter-t barrier #1 from
// iter t-1's reads (all waves' ds_reads completed before their MFMAs consumed them).

#define GEMM_WAIT4() asm volatile("s_waitcnt vmcnt(4)" ::: "memory")
#define GEMM_WAIT0() asm volatile("s_waitcnt vmcnt(0)" ::: "memory")

__global__ __launch_bounds__(256) void gemm_qkv_kernel(
    const unsigned short* __restrict__ A, const unsigned short* __restrict__ BT,
    const float* __restrict__ bq, const float* __restrict__ bk, const float* __restrict__ bv,
    unsigned short* __restrict__ Qo, unsigned short* __restrict__ Ko, unsigned short* __restrict__ VTo) {
    __shared__ unsigned short As[2 * 128 * 64];
    __shared__ unsigned short Bs[2 * 128 * 64];
    const int tid = threadIdx.x;
    const int m0 = blockIdx.y * 128, n0 = blockIdx.x * 128;
    const int w = tid >> 6, lane = tid & 63, lr = lane & 15, quad = lane >> 4;
    const int wy = w >> 1, wx = w & 1;
    f32x4 acc[4][4];
#pragma unroll
    for (int i = 0; i < 4; i++)
#pragma unroll
        for (int j = 0; j < 4; j++) acc[i][j] = (f32x4){0.f, 0.f, 0.f, 0.f};
    const int drow = lane >> 3;              // 8 rows per dma16 (128B rows)
    const int dchunk = (lane & 7) ^ drow;    // source swizzle
    const unsigned short* gA = A + (size_t)(m0 + w * 32 + drow) * 1024 + dchunk * 8;
    const unsigned short* gB = BT + (size_t)(n0 + w * 32 + drow) * 1024 + dchunk * 8;
    const int swav = (w * 32) * 64;
    const int swz = lr & 7;
    // prologue: tile 0, A first then B (wait counts depend on this order)
#pragma unroll
    for (int jj = 0; jj < 4; jj++) dma16(gA + jj * 8 * 1024, As + swav + jj * 8 * 64);
#pragma unroll
    for (int jj = 0; jj < 4; jj++) dma16(gB + jj * 8 * 1024, Bs + swav + jj * 8 * 64);
    for (int t = 0; t < 16; ++t) {
        const int cur = t & 1;
        const unsigned short* cA = As + cur * 8192;
        const unsigned short* cB = Bs + cur * 8192;
        unsigned short* nA = As + (cur ^ 1) * 8192 + swav;
        unsigned short* nB = Bs + (cur ^ 1) * 8192 + swav;
        const int kt = t * 64;
        GEMM_WAIT4();                     // A(t) landed (B(t) may be in flight)
        __builtin_amdgcn_s_barrier();     // prior-iter LDS reads done block-wide
        if (t < 15) {
#pragma unroll
            for (int jj = 0; jj < 4; jj++) dma16(gA + kt + 64 + jj * 8 * 1024, nA + jj * 8 * 64);
            GEMM_WAIT4();                 // B(t) landed (A(t+1) in flight)
        } else {
            GEMM_WAIT0();                 // tail drain, once
        }
        __builtin_amdgcn_s_barrier();     // tile t fully visible to all waves
        bf16x8 bf[4][2];
#pragma unroll
        for (int j = 0; j < 4; j++)
#pragma unroll
            for (int kc = 0; kc < 2; kc++)
                bf[j][kc] = ldfrag(cB + (wx * 64 + j * 16 + lr) * 64 + ((kc * 4 + quad) ^ swz) * 8);
        if (t < 15) {
#pragma unroll
            for (int jj = 0; jj < 4; jj++) dma16(gB + kt + 64 + jj * 8 * 1024, nB + jj * 8 * 64);
        }
#pragma unroll
        for (int i = 0; i < 4; i++) {
            bf16x8 a0 = ldfrag(cA + (wy * 64 + i * 16 + lr) * 64 + ((quad) ^ swz) * 8);
            bf16x8 a1 = ldfrag(cA + (wy * 64 + i * 16 + lr) * 64 + ((4 + quad) ^ swz) * 8);
#pragma unroll
            for (int j = 0; j < 4; j++) {
                acc[i][j] = MFMA_BF16(a0, bf[j][0], acc[i][j]);
                acc[i][j] = MFMA_BF16(a1, bf[j][1], acc[i][j]);
            }
        }
    }
#pragma unroll
    for (int j = 0; j < 4; j++) {
        int n = n0 + wx * 64 + j * 16 + lr;
        int proj = n >> 10, rem = n & 1023, h = rem >> 6, e = rem & 63;
        if (proj == 2) {
            // V: write transposed [bh, e, s] with packed b64 stores down s (RNE pack!)
            float bb = bv[rem];
#pragma unroll
            for (int i = 0; i < 4; i++) {
                int m = m0 + wy * 64 + i * 16 + quad * 4;
                int batch = m >> 11, s = m & 2047;
                u32x2 pk;
                pk[0] = pack_bf16_rne(acc[i][j][0] + bb, acc[i][j][1] + bb);
                pk[1] = pack_bf16_rne(acc[i][j][2] + bb, acc[i][j][3] + bb);
                *(u32x2*)(VTo + (((size_t)batch * 16 + h) * 64 + e) * 2048 + s) = pk;
            }
        } else {
            const float* bias = (proj == 0) ? bq : bk;
            unsigned short* dst = (proj == 0) ? Qo : Ko;
            float bb = bias[rem];
            float scl = (proj == 0) ? QSCALE : 1.0f;
#pragma unroll
            for (int i = 0; i < 4; i++) {
#pragma unroll
                for (int r = 0; r < 4; r++) {
                    int m = m0 + wy * 64 + i * 16 + quad * 4 + r;
                    int batch = m >> 11, s = m & 2047;
                    dst[(((size_t)batch * 16 + h) * 2048 + s) * 64 + e] = f2bf((acc[i][j][r] + bb) * scl);
                }
            }
        }
    }
}

__global__ __launch_bounds__(256) void gemm_out_kernel(
    const unsigned short* __restrict__ A, const unsigned short* __restrict__ BT,
    const float* __restrict__ bo, float* __restrict__ out) {
    __shared__ unsigned short As[2 * 128 * 64];
    __shared__ unsigned short Bs[2 * 128 * 64];
    const int tid = threadIdx.x;
    const int m0 = blockIdx.y * 128, n0 = blockIdx.x * 128;
    const int w = tid >> 6, lane = tid & 63, lr = lane & 15, quad = lane >> 4;
    const int wy = w >> 1, wx = w & 1;
    f32x4 acc[4][4];
#pragma unroll
    for (int i = 0; i < 4; i++)
#pragma unroll
        for (int j = 0; j < 4; j++) acc[i][j] = (f32x4){0.f, 0.f, 0.f, 0.f};
    const int drow = lane >> 3;
    const int dchunk = (lane & 7) ^ drow;
    const unsigned short* gA = A + (size_t)(m0 + w * 32 + drow) * 1024 + dchunk * 8;
    const unsigned short* gB = BT + (size_t)(n0 + w * 32 + drow) * 1024 + dchunk * 8;
    const int swav = (w * 32) * 64;
    const int swz = lr & 7;
#pragma unroll
    for (int jj = 0; jj < 4; jj++) dma16(gA + jj * 8 * 1024, As + swav + jj * 8 * 64);
#pragma unroll
    for (int jj = 0; jj < 4; jj++) dma16(gB + jj * 8 * 1024, Bs + swav + jj * 8 * 64);
    for (int t = 0; t < 16; ++t) {
        const int cur = t & 1;
        const unsigned short* cA = As + cur * 8192;
        const unsigned short* cB = Bs + cur * 8192;
        unsigned short* nA = As + (cur ^ 1) * 8192 + swav;
        unsigned short* nB = Bs + (cur ^ 1) * 8192 + swav;
        const int kt = t * 64;
        GEMM_WAIT4();
        __builtin_amdgcn_s_barrier();
        if (t < 15) {
#pragma unroll
            for (int jj = 0; jj < 4; jj++) dma16(gA + kt + 64 + jj * 8 * 1024, nA + jj * 8 * 64);
            GEMM_WAIT4();
        } else {
            GEMM_WAIT0();
        }
        __builtin_amdgcn_s_barrier();
        bf16x8 bf[4][2];
#pragma unroll
        for (int j = 0; j < 4; j++)
#pragma unroll
            for (int kc = 0; kc < 2; kc++)
                bf[j][kc] = ldfrag(cB + (wx * 64 + j * 16 + lr) * 64 + ((kc * 4 + quad) ^ swz) * 8);
        if (t < 15) {
#pragma unroll
            for (int jj = 0; jj < 4; jj++) dma16(gB + kt + 64 + jj * 8 * 1024, nB + jj * 8 * 64);
        }
#pragma unroll
        for (int i = 0; i < 4; i++) {
            bf16x8 a0 = ldfrag(cA + (wy * 64 + i * 16 + lr) * 64 + ((quad) ^ swz) * 8);
            bf16x8 a1 = ldfrag(cA + (wy * 64 + i * 16 + lr) * 64 + ((4 + quad) ^ swz) * 8);
#pragma unroll
            for (int j = 0; j < 4; j++) {
                acc[i][j] = MFMA_BF16(a0, bf[j][0], acc[i][j]);
                acc[i][j] = MFMA_BF16(a1, bf[j][1], acc[i][j]);
            }
        }
    }
#pragma unroll
    for (int j = 0; j < 4; j++) {
        int n = n0 + wx * 64 + j * 16 + lr;
        float bb = bo[n];
#pragma unroll
        for (int i = 0; i < 4; i++) {
#pragma unroll
            for (int r = 0; r < 4; r++) {
                int m = m0 + wy * 64 + i * 16 + quad * 4 + r;
                out[(size_t)m * 1024 + n] = acc[i][j][r] + bb;
            }
        }
    }
}

// ---------------- flash attention (S^T = K Q^T, no-max softmax, dbuf DMA pipeline) ----------------
// EXACT R2 structure (94.9 µs champion; 5/5 restructures regressed — do not touch).
// P buffer: wave-private 64x64 u16, 16B-chunk XOR swizzle (chunk ^ (row&7)).
// K/V tiles: [2][64][64] u16, source-swizzled: LDS(r,c) = global(r, c ^ (r&7));
// frag reads use chunk (kc*4+quad) ^ (lr&7) -> <=2-way (free) b128.
__global__ __launch_bounds__(256, 2) void attn_fa_kernel(
    const unsigned short* __restrict__ Q, const unsigned short* __restrict__ K,
    const unsigned short* __restrict__ VT, unsigned short* __restrict__ Out) {
    __shared__ unsigned short Ks[2 * 64 * 64];
    __shared__ unsigned short Vs[2 * 64 * 64];
    __shared__ unsigned short Ps[256 * 64];  // wave-private 64-row P regions, XOR-swizzled
    const int bh = blockIdx.x;               // bh on x: all 8 q-blocks of a head share an XCD (id%8)
    const int q0 = blockIdx.y * 256;
    const int tid = threadIdx.x;
    const int w = tid >> 6, lane = tid & 63, lr = lane & 15, quad = lane >> 4;
    const unsigned short* Qh = Q + (size_t)bh * 2048 * 64;
    const unsigned short* Kh = K + (size_t)bh * 2048 * 64;
    const unsigned short* Vh = VT + (size_t)bh * 64 * 2048;

    const f32x4 ZERO4 = {0.f, 0.f, 0.f, 0.f};

    // DMA setup: wave w covers K/V rows w*16 .. w*16+15 (2 instrs of 8 rows each)
    const int drow = lane >> 3;
    const int dchunk = (lane & 7) ^ drow;
    const unsigned short* gK = Kh + (size_t)(w * 16 + drow) * 64 + dchunk * 8;
    const unsigned short* gV = Vh + (size_t)(w * 16 + drow) * 2048 + dchunk * 8;
    const int swav = (w * 16) * 64;
    // prologue: tile 0 -> buf 0
    dma16(gK, Ks + swav);
    dma16(gK + 8 * 64, Ks + swav + 8 * 64);
    dma16(gV, Vs + swav);
    dma16(gV + 8 * 2048, Vs + swav + 8 * 64);

    // Q fragments direct from global (one-time load; stays in regs)
    bf16x8 qb[4][2];  // [q-16-group][kc]
#pragma unroll
    for (int nt = 0; nt < 4; nt++)
#pragma unroll
        for (int kc = 0; kc < 2; kc++)
            qb[nt][kc] = ldfrag(Qh + (size_t)(q0 + w * 64 + nt * 16 + lr) * 64 + kc * 32 + quad * 8);

    f32x4 o[4][4];
#pragma unroll
    for (int i = 0; i < 4; i++)
#pragma unroll
        for (int j = 0; j < 4; j++) o[i][j] = ZERO4;
    float lp[4] = {0.f, 0.f, 0.f, 0.f};

    unsigned short* const Pw = Ps + (w * 64) * 64;  // this wave's private P rows
    const int swzb = lr & 7;                        // row&7 for all P rows this lane touches

    for (int t0 = 0; t0 < 2048; t0 += 64) {
        const int cur = (t0 >> 6) & 1;
        const unsigned short* cK = Ks + cur * 4096;
        const unsigned short* cV = Vs + cur * 4096;
        pipeline_barrier();  // drains this tile's DMA; releases other buffer
        // hoist ALL K/V fragment reads before the prefetch DMA issue
        bf16x8 ka[2][4], vb[2][4];
#pragma unroll
        for (int kc = 0; kc < 2; kc++)
#pragma unroll
            for (int mt = 0; mt < 4; mt++) {
                int fc = ((kc * 4 + quad) ^ swzb) * 8;
                ka[kc][mt] = ldfrag(cK + (mt * 16 + lr) * 64 + fc);
                vb[kc][mt] = ldfrag(cV + (mt * 16 + lr) * 64 + fc);
            }
        if (t0 + 64 < 2048) {  // prefetch next tile into other buffer
            const int nb = (cur ^ 1) * 4096 + swav;
            dma16(gK + (size_t)(t0 + 64) * 64, Ks + nb);
            dma16(gK + (size_t)(t0 + 64) * 64 + 8 * 64, Ks + nb + 8 * 64);
            dma16(gV + t0 + 64, Vs + nb);
            dma16(gV + t0 + 64 + 8 * 2048, Vs + nb + 8 * 64);
        }

        // S^T = K·Q^T, per-mt (16 t-rows): MFMA pair -> exp2 -> pack -> P write.
#pragma unroll
        for (int mt = 0; mt < 4; mt++) {
            f32x4 sc[4];
#pragma unroll
            for (int nt = 0; nt < 4; nt++) {
                f32x4 z = ZERO4;
                sc[nt] = MFMA_BF16(ka[0][mt], qb[nt][0], z);
                sc[nt] = MFMA_BF16(ka[1][mt], qb[nt][1], sc[nt]);
            }
#pragma unroll
            for (int nt = 0; nt < 4; nt++) {
                float p0 = fast_exp2(sc[nt][0]);
                float p1 = fast_exp2(sc[nt][1]);
                float p2 = fast_exp2(sc[nt][2]);
                float p3 = fast_exp2(sc[nt][3]);
                lp[nt] += (p0 + p1) + (p2 + p3);
                u32x2 pk;
                pk[0] = pack_bf16(p0, p1);
                pk[1] = pack_bf16(p2, p3);
                // row = nt*16+lr; 16B chunk (2*mt + quad/2) swizzled by row&7; 8B half = quad&1
                *(u32x2*)(Pw + (nt * 16 + lr) * 64 + ((2 * mt + (quad >> 1)) ^ swzb) * 8 +
                          (quad & 1) * 4) = pk;
            }
        }

        // O += P·V  (A = own-wave P rows — wave-private region, lgkm-ordered)
#pragma unroll
        for (int kc = 0; kc < 2; kc++) {
            const int fc = ((kc * 4 + quad) ^ swzb) * 8;
#pragma unroll
            for (int g = 0; g < 4; g++) {
                bf16x8 pa = ldfrag(Pw + (g * 16 + lr) * 64 + fc);
                o[g][0] = MFMA_BF16(pa, vb[kc][0], o[g][0]);
                o[g][1] = MFMA_BF16(pa, vb[kc][1], o[g][1]);
                o[g][2] = MFMA_BF16(pa, vb[kc][2], o[g][2]);
                o[g][3] = MFMA_BF16(pa, vb[kc][3], o[g][3]);
            }
        }
    }

    // final denominator: reduce across the 4 quads
#pragma unroll
    for (int g = 0; g < 4; g++) {
        float l = lp[g];
        l += __shfl_xor(l, 16, 64);
        l += __shfl_xor(l, 32, 64);
        lp[g] = l;
    }

    // normalize + write attn [B,S,H*E] bf16
    const int h = bh & 15, b = bh >> 4;
#pragma unroll
    for (int g = 0; g < 4; g++) {
#pragma unroll
        for (int r = 0; r < 4; r++) {
            float l = __shfl(lp[g], quad * 4 + r, 16);
            float inv = 1.0f / l;
            int s = q0 + w * 64 + g * 16 + quad * 4 + r;
#pragma unroll
            for (int et = 0; et < 4; et++) {
                int col = h * 64 + et * 16 + lr;
                Out[((size_t)(b * 2048 + s)) * 1024 + col] = f2bf(o[g][et][r] * inv);
            }
        }
    }
}

// ---------------- launch ----------------

extern "C" void kernel_launch(void* const* d_in, const int* in_sizes, int n_in,
                              void* d_out, int out_size, void* d_ws, size_t ws_size,
                              hipStream_t stream) {
    const float* x  = (const float*)d_in[0];
    const float* Wq = (const float*)d_in[1];
    const float* bq = (const float*)d_in[2];
    const float* Wk = (const float*)d_in[3];
    const float* bk = (const float*)d_in[4];
    const float* Wv = (const float*)d_in[5];
    const float* bv = (const float*)d_in[6];
    const float* Wo = (const float*)d_in[7];
    const float* bo = (const float*)d_in[8];
    float* out = (float*)d_out;

    char* ws = (char*)d_ws;
    unsigned short* xb    = (unsigned short*)(ws);              // 16 MiB; reused as attn buffer
    unsigned short* WqkvT = (unsigned short*)(ws + 16777216);   // 6 MiB
    unsigned short* WoT   = (unsigned short*)(ws + 23068672);   // 2 MiB
    unsigned short* Qb    = (unsigned short*)(ws + 25165824);   // 16 MiB
    unsigned short* Kb    = (unsigned short*)(ws + 41943040);   // 16 MiB
    unsigned short* VTb   = (unsigned short*)(ws + 58720256);   // 16 MiB (total 72 MiB)
    unsigned short* attn  = xb;  // xb is dead after gemm_qkv

    cvt_fused_kernel<<<dim3(6144), dim3(256), 0, stream>>>(x, Wq, Wk, Wv, Wo, xb, WqkvT, WoT);
    gemm_qkv_kernel<<<dim3(24, 64), dim3(256), 0, stream>>>(xb, WqkvT, bq, bk, bv, Qb, Kb, VTb);
    attn_fa_kernel<<<dim3(64, 8), dim3(256), 0, stream>>>(Qb, Kb, VTb, attn);
    gemm_out_kernel<<<dim3(8, 64), dim3(256), 0, stream>>>(attn, WoT, bo, out);
}

// Round 11
// 281.780 us; speedup vs baseline: 1.0614x; 1.0614x over previous
//
#include <hip/hip_runtime.h>

typedef __bf16 bf16x8 __attribute__((ext_vector_type(8)));
typedef float f32x4 __attribute__((ext_vector_type(4)));
typedef unsigned int u32x4 __attribute__((ext_vector_type(4)));
typedef unsigned int u32x2 __attribute__((ext_vector_type(2)));
typedef unsigned short u16x8 __attribute__((ext_vector_type(8)));

#define MFMA_BF16(a, b, c) __builtin_amdgcn_mfma_f32_16x16x32_bf16((a), (b), (c), 0, 0, 0)

// 0.125 (1/sqrt(64)) * log2(e): folded into Q so softmax uses raw exp2
#define QSCALE 0.18033688011112043f

__device__ __forceinline__ unsigned short f2bf(float f) {
    unsigned int u = __builtin_bit_cast(unsigned int, f);
    u += 0x7FFFu + ((u >> 16) & 1u);
    return (unsigned short)(u >> 16);
}

// manual RNE pack (bit-identical to f2bf pairs) — numerically sensitive V path stays RNE.
__device__ __forceinline__ unsigned int pack_bf16_rne(float a, float b) {
    unsigned int ua = __builtin_bit_cast(unsigned int, a);
    unsigned int ub = __builtin_bit_cast(unsigned int, b);
    ua += 0x7FFFu + ((ua >> 16) & 1u);
    ub += 0x7FFFu + ((ub >> 16) & 1u);
    return __builtin_amdgcn_perm(ub, ua, 0x07060302);
}

// cheap pack for P (values in [0,1], self-normalizing) — validated earlier
#if __has_builtin(__builtin_amdgcn_cvt_pk_bf16_f32)
typedef __bf16 bf16x2 __attribute__((ext_vector_type(2)));
__device__ __forceinline__ unsigned int pack_bf16(float a, float b) {
    return __builtin_bit_cast(unsigned int, __builtin_amdgcn_cvt_pk_bf16_f32(a, b));
}
#else
__device__ __forceinline__ unsigned int pack_bf16(float a, float b) {
    return pack_bf16_rne(a, b);
}
#endif

#if __has_builtin(__builtin_amdgcn_exp2f)
__device__ __forceinline__ float fast_exp2(float x) { return __builtin_amdgcn_exp2f(x); }
#else
__device__ __forceinline__ float fast_exp2(float x) { return exp2f(x); }
#endif

__device__ __forceinline__ bf16x8 ldfrag(const unsigned short* p) {
    return __builtin_bit_cast(bf16x8, *(const u32x4*)p);
}

// async global->LDS, 16B per lane; LDS dst = wave-uniform base + lane*16B
typedef const __attribute__((address_space(1))) void* gas_t;
typedef __attribute__((address_space(3))) void* las_t;
__device__ __forceinline__ void dma16(const unsigned short* g, unsigned short* l) {
    __builtin_amdgcn_global_load_lds((gas_t)(const void*)g, (las_t)(void*)l, 16, 0, 0);
}

// drain this wave's outstanding DMA/LDS ops, then block barrier.
__device__ __forceinline__ void pipeline_barrier() {
    __builtin_amdgcn_s_waitcnt(0);
    __syncthreads();
}

// ---------------- fused conversion kernel (confirmed -5.4 µs) ----------------
// blocks [0,4096): x -> bf16.  [4096,5632): Wq/Wk/Wv transpose+cvt.  [5632,6144): Wo^T cvt.

__global__ void cvt_fused_kernel(const float* __restrict__ x,
                                 const float* __restrict__ Wq, const float* __restrict__ Wk,
                                 const float* __restrict__ Wv, const float* __restrict__ Wo,
                                 unsigned short* __restrict__ xb, unsigned short* __restrict__ WT,
                                 unsigned short* __restrict__ WoT) {
    const int b = blockIdx.x;
    const int tid = threadIdx.x;
    if (b < 4096) {
        long long t = (long long)b * 256 + tid;
        const f32x4* p = (const f32x4*)x + t * 2;
        f32x4 v0 = p[0], v1 = p[1];
        u16x8 o;
        o[0] = f2bf(v0[0]); o[1] = f2bf(v0[1]); o[2] = f2bf(v0[2]); o[3] = f2bf(v0[3]);
        o[4] = f2bf(v1[0]); o[5] = f2bf(v1[1]); o[6] = f2bf(v1[2]); o[7] = f2bf(v1[3]);
        *((u16x8*)xb + t) = o;
    } else if (b < 5632) {
        int bb = b - 4096;
        int bx = bb % 12, by = bb / 12;
        int n = bx * 256 + tid;
        int d0 = by * 8;
        int proj = n >> 10, rem = n & 1023, h = rem >> 6, e = rem & 63;
        const float* W = (proj == 0) ? Wq : (proj == 1) ? Wk : Wv;
        const float* src = W + (size_t)h * 65536 + (size_t)d0 * 64 + e;
        u16x8 o;
#pragma unroll
        for (int j = 0; j < 8; j++) o[j] = f2bf(src[j * 64]);
        *(u16x8*)(WT + (size_t)n * 1024 + d0) = o;
    } else {
        int bb = b - 5632;
        int bx = bb % 4, by = bb / 4;
        int n = bx * 256 + tid;
        int d0 = by * 8;
        const float* src = Wo + (size_t)d0 * 1024 + n;
        u16x8 o;
#pragma unroll
        for (int j = 0; j < 8; j++) o[j] = f2bf(src[j * 1024]);
        *(u16x8*)(WoT + (size_t)n * 1024 + d0) = o;
    }
}

// ---------------- GEMM kernels: single-barrier double-buffered DMA pipeline ----------------
// EXACT R2 form (champion). LDS: [2][128][32] u16 per operand = 32 KiB/block -> 4 blocks/CU
// (VGPR-capped). R10's BK=64 counted-vmcnt variant FALSIFIED: 64 KiB LDS halved residency
// to 2 blocks/CU (m132's lesson) and lost 13 µs. Do not grow BK without the full 8-phase
// schedule (T3+T4 regime gate, m230).
// LDS(r,c-chunk) = global(r, c ^ (r&3)); frag chunk = quad ^ (lr&3).

__global__ __launch_bounds__(256) void gemm_qkv_kernel(
    const unsigned short* __restrict__ A, const unsigned short* __restrict__ BT,
    const float* __restrict__ bq, const float* __restrict__ bk, const float* __restrict__ bv,
    unsigned short* __restrict__ Qo, unsigned short* __restrict__ Ko, unsigned short* __restrict__ VTo) {
    __shared__ unsigned short As[2 * 128 * 32];
    __shared__ unsigned short Bs[2 * 128 * 32];
    const int tid = threadIdx.x;
    const int m0 = blockIdx.y * 128, n0 = blockIdx.x * 128;
    const int w = tid >> 6, lane = tid & 63, lr = lane & 15, quad = lane >> 4;
    const int wy = w >> 1, wx = w & 1;
    f32x4 acc[4][4];
#pragma unroll
    for (int i = 0; i < 4; i++)
#pragma unroll
        for (int j = 0; j < 4; j++) acc[i][j] = (f32x4){0.f, 0.f, 0.f, 0.f};
    const int drow = lane >> 2;
    const int dchunk = (lane & 3) ^ (drow & 3);
    const unsigned short* gA = A + (size_t)(m0 + w * 32 + drow) * 1024 + dchunk * 8;
    const unsigned short* gB = BT + (size_t)(n0 + w * 32 + drow) * 1024 + dchunk * 8;
    const int swav = (w * 32) * 32;
    const int fcol = (quad ^ (lr & 3)) * 8;
    // prologue: tile 0 -> buf 0
    dma16(gA, As + swav);
    dma16(gA + 16 * 1024, As + swav + 16 * 32);
    dma16(gB, Bs + swav);
    dma16(gB + 16 * 1024, Bs + swav + 16 * 32);
    for (int k0 = 0; k0 < 1024; k0 += 32) {
        const int cur = (k0 >> 5) & 1;
        const unsigned short* cA = As + cur * 4096;
        const unsigned short* cB = Bs + cur * 4096;
        pipeline_barrier();  // drains this wave's DMA for tile k0; releases buf[cur^1]
        bf16x8 af[4], bfr[4];
#pragma unroll
        for (int i = 0; i < 4; i++) af[i] = ldfrag(cA + (wy * 64 + i * 16 + lr) * 32 + fcol);
#pragma unroll
        for (int j = 0; j < 4; j++) bfr[j] = ldfrag(cB + (wx * 64 + j * 16 + lr) * 32 + fcol);
        if (k0 + 32 < 1024) {  // prefetch tile k0+32 into other buffer
            const int nb = (cur ^ 1) * 4096 + swav;
            dma16(gA + k0 + 32, As + nb);
            dma16(gA + k0 + 32 + 16 * 1024, As + nb + 16 * 32);
            dma16(gB + k0 + 32, Bs + nb);
            dma16(gB + k0 + 32 + 16 * 1024, Bs + nb + 16 * 32);
        }
#pragma unroll
        for (int i = 0; i < 4; i++)
#pragma unroll
            for (int j = 0; j < 4; j++) acc[i][j] = MFMA_BF16(af[i], bfr[j], acc[i][j]);
    }
#pragma unroll
    for (int j = 0; j < 4; j++) {
        int n = n0 + wx * 64 + j * 16 + lr;
        int proj = n >> 10, rem = n & 1023, h = rem >> 6, e = rem & 63;
        if (proj == 2) {
            // V: write transposed [bh, e, s] with packed b64 stores down s (RNE pack!)
            float bb = bv[rem];
#pragma unroll
            for (int i = 0; i < 4; i++) {
                int m = m0 + wy * 64 + i * 16 + quad * 4;
                int batch = m >> 11, s = m & 2047;
                u32x2 pk;
                pk[0] = pack_bf16_rne(acc[i][j][0] + bb, acc[i][j][1] + bb);
                pk[1] = pack_bf16_rne(acc[i][j][2] + bb, acc[i][j][3] + bb);
                *(u32x2*)(VTo + (((size_t)batch * 16 + h) * 64 + e) * 2048 + s) = pk;
            }
        } else {
            const float* bias = (proj == 0) ? bq : bk;
            unsigned short* dst = (proj == 0) ? Qo : Ko;
            float bb = bias[rem];
            float scl = (proj == 0) ? QSCALE : 1.0f;
#pragma unroll
            for (int i = 0; i < 4; i++) {
#pragma unroll
                for (int r = 0; r < 4; r++) {
                    int m = m0 + wy * 64 + i * 16 + quad * 4 + r;
                    int batch = m >> 11, s = m & 2047;
                    dst[(((size_t)batch * 16 + h) * 2048 + s) * 64 + e] = f2bf((acc[i][j][r] + bb) * scl);
                }
            }
        }
    }
}

__global__ __launch_bounds__(256) void gemm_out_kernel(
    const unsigned short* __restrict__ A, const unsigned short* __restrict__ BT,
    const float* __restrict__ bo, float* __restrict__ out) {
    __shared__ unsigned short As[2 * 128 * 32];
    __shared__ unsigned short Bs[2 * 128 * 32];
    const int tid = threadIdx.x;
    const int m0 = blockIdx.y * 128, n0 = blockIdx.x * 128;
    const int w = tid >> 6, lane = tid & 63, lr = lane & 15, quad = lane >> 4;
    const int wy = w >> 1, wx = w & 1;
    f32x4 acc[4][4];
#pragma unroll
    for (int i = 0; i < 4; i++)
#pragma unroll
        for (int j = 0; j < 4; j++) acc[i][j] = (f32x4){0.f, 0.f, 0.f, 0.f};
    const int drow = lane >> 2;
    const int dchunk = (lane & 3) ^ (drow & 3);
    const unsigned short* gA = A + (size_t)(m0 + w * 32 + drow) * 1024 + dchunk * 8;
    const unsigned short* gB = BT + (size_t)(n0 + w * 32 + drow) * 1024 + dchunk * 8;
    const int swav = (w * 32) * 32;
    const int fcol = (quad ^ (lr & 3)) * 8;
    dma16(gA, As + swav);
    dma16(gA + 16 * 1024, As + swav + 16 * 32);
    dma16(gB, Bs + swav);
    dma16(gB + 16 * 1024, Bs + swav + 16 * 32);
    for (int k0 = 0; k0 < 1024; k0 += 32) {
        const int cur = (k0 >> 5) & 1;
        const unsigned short* cA = As + cur * 4096;
        const unsigned short* cB = Bs + cur * 4096;
        pipeline_barrier();
        bf16x8 af[4], bfr[4];
#pragma unroll
        for (int i = 0; i < 4; i++) af[i] = ldfrag(cA + (wy * 64 + i * 16 + lr) * 32 + fcol);
#pragma unroll
        for (int j = 0; j < 4; j++) bfr[j] = ldfrag(cB + (wx * 64 + j * 16 + lr) * 32 + fcol);
        if (k0 + 32 < 1024) {
            const int nb = (cur ^ 1) * 4096 + swav;
            dma16(gA + k0 + 32, As + nb);
            dma16(gA + k0 + 32 + 16 * 1024, As + nb + 16 * 32);
            dma16(gB + k0 + 32, Bs + nb);
            dma16(gB + k0 + 32 + 16 * 1024, Bs + nb + 16 * 32);
        }
#pragma unroll
        for (int i = 0; i < 4; i++)
#pragma unroll
            for (int j = 0; j < 4; j++) acc[i][j] = MFMA_BF16(af[i], bfr[j], acc[i][j]);
    }
#pragma unroll
    for (int j = 0; j < 4; j++) {
        int n = n0 + wx * 64 + j * 16 + lr;
        float bb = bo[n];
#pragma unroll
        for (int i = 0; i < 4; i++) {
#pragma unroll
            for (int r = 0; r < 4; r++) {
                int m = m0 + wy * 64 + i * 16 + quad * 4 + r;
                out[(size_t)m * 1024 + n] = acc[i][j][r] + bb;
            }
        }
    }
}

// ---------------- flash attention (S^T = K Q^T, no-max softmax, dbuf DMA pipeline) ----------------
// EXACT R2 structure (94.9 µs champion; 5/5 restructures regressed — do not touch).
// setprio removed (R8/R9 A/B: +2.7 µs harm in this barrier-locksteped structure).
// P buffer: wave-private 64x64 u16, 16B-chunk XOR swizzle (chunk ^ (row&7)).
// K/V tiles: [2][64][64] u16, source-swizzled: LDS(r,c) = global(r, c ^ (r&7));
// frag reads use chunk (kc*4+quad) ^ (lr&7) -> <=2-way (free) b128.
__global__ __launch_bounds__(256, 2) void attn_fa_kernel(
    const unsigned short* __restrict__ Q, const unsigned short* __restrict__ K,
    const unsigned short* __restrict__ VT, unsigned short* __restrict__ Out) {
    __shared__ unsigned short Ks[2 * 64 * 64];
    __shared__ unsigned short Vs[2 * 64 * 64];
    __shared__ unsigned short Ps[256 * 64];  // wave-private 64-row P regions, XOR-swizzled
    const int bh = blockIdx.x;               // bh on x: all 8 q-blocks of a head share an XCD (id%8)
    const int q0 = blockIdx.y * 256;
    const int tid = threadIdx.x;
    const int w = tid >> 6, lane = tid & 63, lr = lane & 15, quad = lane >> 4;
    const unsigned short* Qh = Q + (size_t)bh * 2048 * 64;
    const unsigned short* Kh = K + (size_t)bh * 2048 * 64;
    const unsigned short* Vh = VT + (size_t)bh * 64 * 2048;

    const f32x4 ZERO4 = {0.f, 0.f, 0.f, 0.f};

    // DMA setup: wave w covers K/V rows w*16 .. w*16+15 (2 instrs of 8 rows each)
    const int drow = lane >> 3;
    const int dchunk = (lane & 7) ^ drow;
    const unsigned short* gK = Kh + (size_t)(w * 16 + drow) * 64 + dchunk * 8;
    const unsigned short* gV = Vh + (size_t)(w * 16 + drow) * 2048 + dchunk * 8;
    const int swav = (w * 16) * 64;
    // prologue: tile 0 -> buf 0
    dma16(gK, Ks + swav);
    dma16(gK + 8 * 64, Ks + swav + 8 * 64);
    dma16(gV, Vs + swav);
    dma16(gV + 8 * 2048, Vs + swav + 8 * 64);

    // Q fragments direct from global (one-time load; stays in regs)
    bf16x8 qb[4][2];  // [q-16-group][kc]
#pragma unroll
    for (int nt = 0; nt < 4; nt++)
#pragma unroll
        for (int kc = 0; kc < 2; kc++)
            qb[nt][kc] = ldfrag(Qh + (size_t)(q0 + w * 64 + nt * 16 + lr) * 64 + kc * 32 + quad * 8);

    f32x4 o[4][4];
#pragma unroll
    for (int i = 0; i < 4; i++)
#pragma unroll
        for (int j = 0; j < 4; j++) o[i][j] = ZERO4;
    float lp[4] = {0.f, 0.f, 0.f, 0.f};

    unsigned short* const Pw = Ps + (w * 64) * 64;  // this wave's private P rows
    const int swzb = lr & 7;                        // row&7 for all P rows this lane touches

    for (int t0 = 0; t0 < 2048; t0 += 64) {
        const int cur = (t0 >> 6) & 1;
        const unsigned short* cK = Ks + cur * 4096;
        const unsigned short* cV = Vs + cur * 4096;
        pipeline_barrier();  // drains this tile's DMA; releases other buffer
        // hoist ALL K/V fragment reads before the prefetch DMA issue
        bf16x8 ka[2][4], vb[2][4];
#pragma unroll
        for (int kc = 0; kc < 2; kc++)
#pragma unroll
            for (int mt = 0; mt < 4; mt++) {
                int fc = ((kc * 4 + quad) ^ swzb) * 8;
                ka[kc][mt] = ldfrag(cK + (mt * 16 + lr) * 64 + fc);
                vb[kc][mt] = ldfrag(cV + (mt * 16 + lr) * 64 + fc);
            }
        if (t0 + 64 < 2048) {  // prefetch next tile into other buffer
            const int nb = (cur ^ 1) * 4096 + swav;
            dma16(gK + (size_t)(t0 + 64) * 64, Ks + nb);
            dma16(gK + (size_t)(t0 + 64) * 64 + 8 * 64, Ks + nb + 8 * 64);
            dma16(gV + t0 + 64, Vs + nb);
            dma16(gV + t0 + 64 + 8 * 2048, Vs + nb + 8 * 64);
        }

        // S^T = K·Q^T, per-mt (16 t-rows): MFMA pair -> exp2 -> pack -> P write.
#pragma unroll
        for (int mt = 0; mt < 4; mt++) {
            f32x4 sc[4];
#pragma unroll
            for (int nt = 0; nt < 4; nt++) {
                f32x4 z = ZERO4;
                sc[nt] = MFMA_BF16(ka[0][mt], qb[nt][0], z);
                sc[nt] = MFMA_BF16(ka[1][mt], qb[nt][1], sc[nt]);
            }
#pragma unroll
            for (int nt = 0; nt < 4; nt++) {
                float p0 = fast_exp2(sc[nt][0]);
                float p1 = fast_exp2(sc[nt][1]);
                float p2 = fast_exp2(sc[nt][2]);
                float p3 = fast_exp2(sc[nt][3]);
                lp[nt] += (p0 + p1) + (p2 + p3);
                u32x2 pk;
                pk[0] = pack_bf16(p0, p1);
                pk[1] = pack_bf16(p2, p3);
                // row = nt*16+lr; 16B chunk (2*mt + quad/2) swizzled by row&7; 8B half = quad&1
                *(u32x2*)(Pw + (nt * 16 + lr) * 64 + ((2 * mt + (quad >> 1)) ^ swzb) * 8 +
                          (quad & 1) * 4) = pk;
            }
        }

        // O += P·V  (A = own-wave P rows — wave-private region, lgkm-ordered)
#pragma unroll
        for (int kc = 0; kc < 2; kc++) {
            const int fc = ((kc * 4 + quad) ^ swzb) * 8;
#pragma unroll
            for (int g = 0; g < 4; g++) {
                bf16x8 pa = ldfrag(Pw + (g * 16 + lr) * 64 + fc);
                o[g][0] = MFMA_BF16(pa, vb[kc][0], o[g][0]);
                o[g][1] = MFMA_BF16(pa, vb[kc][1], o[g][1]);
                o[g][2] = MFMA_BF16(pa, vb[kc][2], o[g][2]);
                o[g][3] = MFMA_BF16(pa, vb[kc][3], o[g][3]);
            }
        }
    }

    // final denominator: reduce across the 4 quads
#pragma unroll
    for (int g = 0; g < 4; g++) {
        float l = lp[g];
        l += __shfl_xor(l, 16, 64);
        l += __shfl_xor(l, 32, 64);
        lp[g] = l;
    }

    // normalize + write attn [B,S,H*E] bf16
    const int h = bh & 15, b = bh >> 4;
#pragma unroll
    for (int g = 0; g < 4; g++) {
#pragma unroll
        for (int r = 0; r < 4; r++) {
            float l = __shfl(lp[g], quad * 4 + r, 16);
            float inv = 1.0f / l;
            int s = q0 + w * 64 + g * 16 + quad * 4 + r;
#pragma unroll
            for (int et = 0; et < 4; et++) {
                int col = h * 64 + et * 16 + lr;
                Out[((size_t)(b * 2048 + s)) * 1024 + col] = f2bf(o[g][et][r] * inv);
            }
        }
    }
}

// ---------------- launch ----------------

extern "C" void kernel_launch(void* const* d_in, const int* in_sizes, int n_in,
                              void* d_out, int out_size, void* d_ws, size_t ws_size,
                              hipStream_t stream) {
    const float* x  = (const float*)d_in[0];
    const float* Wq = (const float*)d_in[1];
    const float* bq = (const float*)d_in[2];
    const float* Wk = (const float*)d_in[3];
    const float* bk = (const float*)d_in[4];
    const float* Wv = (const float*)d_in[5];
    const float* bv = (const float*)d_in[6];
    const float* Wo = (const float*)d_in[7];
    const float* bo = (const float*)d_in[8];
    float* out = (float*)d_out;

    char* ws = (char*)d_ws;
    unsigned short* xb    = (unsigned short*)(ws);              // 16 MiB; reused as attn buffer
    unsigned short* WqkvT = (unsigned short*)(ws + 16777216);   // 6 MiB
    unsigned short* WoT   = (unsigned short*)(ws + 23068672);   // 2 MiB
    unsigned short* Qb    = (unsigned short*)(ws + 25165824);   // 16 MiB
    unsigned short* Kb    = (unsigned short*)(ws + 41943040);   // 16 MiB
    unsigned short* VTb   = (unsigned short*)(ws + 58720256);   // 16 MiB (total 72 MiB)
    unsigned short* attn  = xb;  // xb is dead after gemm_qkv

    cvt_fused_kernel<<<dim3(6144), dim3(256), 0, stream>>>(x, Wq, Wk, Wv, Wo, xb, WqkvT, WoT);
    gemm_qkv_kernel<<<dim3(24, 64), dim3(256), 0, stream>>>(xb, WqkvT, bq, bk, bv, Qb, Kb, VTb);
    attn_fa_kernel<<<dim3(64, 8), dim3(256), 0, stream>>>(Qb, Kb, VTb, attn);
    gemm_out_kernel<<<dim3(8, 64), dim3(256), 0, stream>>>(attn, WoT, bo, out);
}